// Round 7
// baseline (343.615 us; speedup 1.0000x reference)
//
#include <hip/hip_runtime.h>

typedef unsigned int   u32;
typedef unsigned short u16;

typedef _Float16 h2  __attribute__((ext_vector_type(2)));
typedef _Float16 h8  __attribute__((ext_vector_type(8)));
typedef float    f32x4 __attribute__((ext_vector_type(4)));

#define M_TOK 128

__device__ __forceinline__ u16 f2h_(float f) {
    _Float16 h = (_Float16)f; return __builtin_bit_cast(u16, h);
}
__device__ __forceinline__ float h2f_(u16 b) {
    _Float16 h = __builtin_bit_cast(_Float16, b); return (float)h;
}
__device__ __forceinline__ void acc8(uint4 v, float* s) {
#pragma unroll
    for (int i = 0; i < 4; ++i) {
        u32 w = ((const u32*)&v)[i];
        s[2 * i]     += h2f_((u16)(w & 0xFFFF));
        s[2 * i + 1] += h2f_((u16)(w >> 16));
    }
}

// AWQ nibble order: n&7 = j sits at bit position SH[j]
__constant__ int SHC[8] = {0, 16, 4, 20, 8, 24, 12, 28};

// ---------------------------------------------------------------------------
// pack_zs: (qz, sc) -> zs[g][n] u32 { lo16: fp16(-(1024+z)), hi16: fp16(sc) }
// ---------------------------------------------------------------------------
__launch_bounds__(256)
__global__ void pack_zs(const int* __restrict__ qz, const float* __restrict__ sc,
                        u32* __restrict__ zs, int qws, int scs, int Ncols, int total) {
    const int idx = blockIdx.x * 256 + threadIdx.x;
    if (idx >= total) return;
    const int g = idx / Ncols, n = idx - g * Ncols;
    const u32 d = (u32)qz[(size_t)g * qws + (n >> 3)];
    const u32 zj = (d >> SHC[n & 7]) & 15u;
    const u32 mz = 0xE400u | zj;                    // fp16 -(1024+z)
    const u16 sh = f2h_(sc[(size_t)g * scs + n]);
    zs[(size_t)g * Ncols + n] = mz | ((u32)sh << 16);
}

// A-fragment-major layout: elem offset for logical (m, k):
//   kb=k/32, q=(k/8)&3, j=k&7, mt=m/16, l16=m&15
//   off = ((kb*8+mt)*64 + q*16 + l16)*8 + j    (fp16 elements)

// ---------------------------------------------------------------------------
// RMSNorm: one block per token row, fp32 in -> fp16 out in Afrag layout
// ---------------------------------------------------------------------------
__launch_bounds__(256)
__global__ void rmsnorm_k(const float* __restrict__ in, const float* __restrict__ w,
                          u16* __restrict__ out) {
    const int row = blockIdx.x;
    const float* x = in + (size_t)row * 4096;
    float ss = 0.f;
#pragma unroll
    for (int j = 0; j < 16; ++j) {
        float v = x[threadIdx.x + 256 * j];
        ss += v * v;
    }
#pragma unroll
    for (int off = 32; off > 0; off >>= 1) ss += __shfl_down(ss, off, 64);
    __shared__ float ws4[4];
    if ((threadIdx.x & 63) == 0) ws4[threadIdx.x >> 6] = ss;
    __syncthreads();
    float total = ws4[0] + ws4[1] + ws4[2] + ws4[3];
    float r = rsqrtf(total * (1.f / 4096.f) + 1e-6f);
    const int mt = row >> 4, l16 = row & 15;
#pragma unroll
    for (int c2 = 0; c2 < 2; ++c2) {
        int c = threadIdx.x * 2 + c2;
        int kb = c >> 2, qq = c & 3;
        u16 o8[8];
#pragma unroll
        for (int j = 0; j < 8; ++j) {
            int i = c * 8 + j;
            o8[j] = f2h_(x[i] * r * w[i]);
        }
        *(uint4*)(out + ((size_t)(kb * 8 + mt) * 64 + qq * 16 + l16) * 8) = *(const uint4*)o8;
    }
}

// ---------------------------------------------------------------------------
// AWQ GEMM, barrier-free, high-occupancy variant.
// Per wave: 128m x 16n strip, BK=64/iter, private LDS B (in-order, no barrier).
// Block = 4 waves = 64n. qw: per-lane row dwordx2 + ds_bpermute route.
// zs: prepacked fp16 pairs. Split-K fp16 partial planes.
// ---------------------------------------------------------------------------
__launch_bounds__(256, 4)
__global__ void gemm_awq(const u16* __restrict__ A, const u32* __restrict__ zs,
                         const int* __restrict__ qw, u16* __restrict__ part,
                         int qws, int N, int K, int kchunk) {
    __shared__ __align__(16) char ldsB[4 * 2304];   // per-wave 16 rows x 144 B

    const int tid = threadIdx.x, w = tid >> 6, lane = tid & 63;
    const int q = lane >> 4, l16 = lane & 15;
    const int n0w = blockIdx.x * 64 + w * 16;
    const int pc0 = n0w >> 3;                       // 2 packed cols per strip
    const int kp = lane & 31, h = lane >> 5;        // k-pair, octet select
    const int sk = blockIdx.y, kc0 = sk * kchunk, kend = min(kc0 + kchunk, K);

    char* myB   = ldsB + w * 2304;
    char* wbase = myB + kp * 4;
    const u16* Ala = A + lane * 8;
    const int* qws_base = qw + pc0;
    const u32* zsO = zs + n0w + h * 8;

    f32x4 acc[8] = {};
    uint4 za0, za1;                 // current group's packed (mz, sc), 8 n

    auto ldraw = [&](int k0) -> uint2 {
        return *(const uint2*)(qws_base + (size_t)(k0 + lane) * qws);
    };
    auto loadzs = [&](int g) {
        za0 = *(const uint4*)(zsO + (size_t)g * N);
        za1 = *(const uint4*)(zsO + (size_t)g * N + 4);
    };
    auto route = [&](uint2 rv, u32& w0, u32& w1) {
        const int i0 = kp * 8, i1 = i0 + 4;         // byte addrs of lanes 2kp, 2kp+1
        int b00 = __builtin_amdgcn_ds_bpermute(i0, (int)rv.x);
        int b01 = __builtin_amdgcn_ds_bpermute(i1, (int)rv.x);
        int b10 = __builtin_amdgcn_ds_bpermute(i0, (int)rv.y);
        int b11 = __builtin_amdgcn_ds_bpermute(i1, (int)rv.y);
        w0 = (u32)(h ? b10 : b00);                  // row 2kp,   col pc0+h
        w1 = (u32)(h ? b11 : b01);                  // row 2kp+1, col pc0+h
    };
    // dequant this lane's octet (8 n) at k-pair kp
    auto emit8 = [&](u32 w0, u32 w1, uint4 z0, uint4 z1) {
        char* bb = wbase + (h * 8) * 144;
        u32 w0s = w0 >> 4, w1s = w1 >> 4;
        auto em = [&](int j, u32 a0, u32 a1, int b, u32 zsj) {
            h2 mz = __builtin_bit_cast(h2, __builtin_amdgcn_perm(zsj, zsj, 0x01000100u));
            h2 s2 = __builtin_bit_cast(h2, __builtin_amdgcn_perm(zsj, zsj, 0x03020302u));
            u32 t = __builtin_amdgcn_perm(a1, a0, (u32)(b | ((b + 4) << 16)));
            u32 u = (t & 0x000F000Fu) | 0x64006400u;
            h2 v = (__builtin_bit_cast(h2, u) + mz) * s2;
            *(u32*)(bb + j * 144) = __builtin_bit_cast(u32, v);
        };
        em(0, w0, w1, 0, z0.x);  em(4, w0, w1, 1, z1.x);
        em(1, w0, w1, 2, z0.y);  em(5, w0, w1, 3, z1.y);
        em(2, w0s, w1s, 0, z0.z); em(6, w0s, w1s, 1, z1.z);
        em(3, w0s, w1s, 2, z0.w); em(7, w0s, w1s, 3, z1.w);
    };

    uint2 rv_n = {0, 0};

    // ---- prologue: dequant step 0, prefetch raw(1) ----
    loadzs(kc0 >> 7);
    uint2 rv0 = ldraw(kc0);
    if (kc0 + 64 < kend) rv_n = ldraw(kc0 + 64);
    {
        u32 w0, w1;
        route(rv0, w0, w1);
        emit8(w0, w1, za0, za1);
    }
    if (((kc0 + 64) & 127) == 0 && kc0 + 64 < kend)
        loadzs((kc0 + 64) >> 7);        // mid-group chunk start (dn odd sk)

    // ---- barrier-free main loop ----
    for (int k0 = kc0; k0 < kend; k0 += 64) {
        const bool kn1 = (k0 + 64) < kend, kn2 = (k0 + 128) < kend;
        const int kb0 = k0 >> 5;
        // B-frags for step i — BOTH halves read before dequant(i+1) writes
        uint4 bv0 = *(const uint4*)(myB + l16 * 144 + q * 16);
        uint4 bv1 = *(const uint4*)(myB + l16 * 144 + 64 + q * 16);
        // A half 0 (issued early; consumed after dequant VALU block)
        uint4 af0[8];
#pragma unroll
        for (int mt = 0; mt < 8; ++mt)
            af0[mt] = *(const uint4*)(Ala + (size_t)(kb0 * 8 + mt) * 512);
        // raw(i+2)
        uint2 rv_f = {0, 0};
        if (kn2) rv_f = ldraw(k0 + 128);
        // dequant(i+1) into same private region (in-order LDS after reads)
        if (kn1) {
            u32 w0, w1;
            route(rv_n, w0, w1);
            emit8(w0, w1, za0, za1);
        }
        if (kn2 && (((k0 + 128) & 127) == 0))
            loadzs((k0 + 128) >> 7);
        // MFMA half 0
#pragma unroll
        for (int mt = 0; mt < 8; ++mt)
            acc[mt] = __builtin_amdgcn_mfma_f32_16x16x32_f16(
                __builtin_bit_cast(h8, af0[mt]), __builtin_bit_cast(h8, bv0),
                acc[mt], 0, 0, 0);
        // A half 1 + MFMA half 1
        uint4 af1[8];
#pragma unroll
        for (int mt = 0; mt < 8; ++mt)
            af1[mt] = *(const uint4*)(Ala + (size_t)((kb0 + 1) * 8 + mt) * 512);
#pragma unroll
        for (int mt = 0; mt < 8; ++mt)
            acc[mt] = __builtin_amdgcn_mfma_f32_16x16x32_f16(
                __builtin_bit_cast(h8, af1[mt]), __builtin_bit_cast(h8, bv1),
                acc[mt], 0, 0, 0);
        rv_n = rv_f;
    }

    // ---- epilogue: fp16 partial store ----
    u16* pp = part + (size_t)sk * M_TOK * N;
    const int n = n0w + l16;
#pragma unroll
    for (int mt = 0; mt < 8; ++mt)
#pragma unroll
        for (int r = 0; r < 4; ++r) {
            const int m = mt * 16 + q * 4 + r;
            pp[(size_t)m * N + n] = f2h_(acc[mt][r]);
        }
}

// ---------------------------------------------------------------------------
__launch_bounds__(256)
__global__ void reduce_to_afrag(const u16* __restrict__ part, u16* __restrict__ out,
                                int SK) {
    const int idx = blockIdx.x * 256 + threadIdx.x;
    const int m = idx >> 9, c = idx & 511;
    float s[8] = {};
    for (int k = 0; k < SK; ++k)
        acc8(*(const uint4*)(part + (size_t)k * 524288 + (size_t)m * 4096 + c * 8), s);
    const int kb = c >> 2, qq = c & 3, mt = m >> 4, l16 = m & 15;
    u16 o8[8];
#pragma unroll
    for (int j = 0; j < 8; ++j) o8[j] = f2h_(s[j]);
    *(uint4*)(out + ((size_t)(kb * 8 + mt) * 64 + qq * 16 + l16) * 8) = *(const uint4*)o8;
}

__launch_bounds__(256)
__global__ void reduce_add_f32(const u16* __restrict__ part, const float* __restrict__ resin,
                               float* __restrict__ out, int SK) {
    const int idx = blockIdx.x * 256 + threadIdx.x;
    const size_t base = (size_t)idx * 8;
    float s[8];
    *(float4*)&s[0] = *(const float4*)(resin + base);
    *(float4*)&s[4] = *(const float4*)(resin + base + 4);
    for (int k = 0; k < SK; ++k)
        acc8(*(const uint4*)(part + (size_t)k * 524288 + base), s);
    *(float4*)(out + base)     = *(const float4*)&s[0];
    *(float4*)(out + base + 4) = *(const float4*)&s[4];
}

__launch_bounds__(256)
__global__ void silu_mul(const u16* __restrict__ part, u16* __restrict__ act) {
    const int idx = blockIdx.x * 256 + threadIdx.x;
    const int m = idx / 1376, c = idx - m * 1376;
    const int nb = c * 8;
    float g[8] = {}, u[8] = {};
    for (int k = 0; k < 3; ++k) {
        const size_t base = (size_t)k * 2818048 + (size_t)m * 22016 + nb;
        acc8(*(const uint4*)(part + base), g);
        acc8(*(const uint4*)(part + base + 11008), u);
    }
    const int kb = nb >> 5, qq = (nb >> 3) & 3, mt = m >> 4, l16 = m & 15;
    u16 o8[8];
#pragma unroll
    for (int j = 0; j < 8; ++j) {
        float a = g[j] / (1.f + __expf(-g[j])) * u[j];
        o8[j] = f2h_(a);
    }
    *(uint4*)(act + ((size_t)(kb * 8 + mt) * 64 + qq * 16 + l16) * 8) = *(const uint4*)o8;
}

// ---------------------------------------------------------------------------
extern "C" void kernel_launch(void* const* d_in, const int* in_sizes, int n_in,
                              void* d_out, int out_size, void* d_ws, size_t ws_size,
                              hipStream_t stream) {
    const float* x      = (const float*)d_in[0];
    const float* ln1_w  = (const float*)d_in[1];
    const float* ln2_w  = (const float*)d_in[2];
    const int*   qkv_qw = (const int*)d_in[3];
    const int*   qkv_qz = (const int*)d_in[4];
    const float* qkv_sc = (const float*)d_in[5];
    const int*   o_qw   = (const int*)d_in[6];
    const int*   o_qz   = (const int*)d_in[7];
    const float* o_sc   = (const float*)d_in[8];
    const int*   gu_qw  = (const int*)d_in[9];
    const int*   gu_qz  = (const int*)d_in[10];
    const float* gu_sc  = (const float*)d_in[11];
    const int*   dn_qw  = (const int*)d_in[12];
    const int*   dn_qz  = (const int*)d_in[13];
    const float* dn_sc  = (const float*)d_in[14];
    float* out = (float*)d_out;

    // ws layout (~25.7 MB, same as R6 which passed)
    char* ws = (char*)d_ws;
    u16*   pbuf = (u16*)(ws);                 // partials: max 16.9 MB (gu SK3)
    u32*   zsb  = (u32*)(ws + 16908288);      // 2.82 MB, reused per gemm
    u16*   act  = (u16*)(ws + 19726336);      // 2.75 MB fp16 (Afrag)
    float* res2 = (float*)(ws + 22544384);    // 2 MB fp32
    u16*   slot = (u16*)(ws + 24641536);      // 1 MB fp16 Afrag (h1/qb/h2)

    // h1 = rmsnorm(x, ln1) -> Afrag ; zs for qkv
    rmsnorm_k<<<128, 256, 0, stream>>>(x, ln1_w, slot);
    pack_zs<<<512, 256, 0, stream>>>(qkv_qz, qkv_sc, zsb, 1536, 12288, 4096, 131072);

    // q = h1 @ Wqkv[:, :4096]   (64 tiles x SK16, kchunk 256)
    gemm_awq<<<dim3(64, 16), 256, 0, stream>>>(slot, zsb, qkv_qw, pbuf,
                                               1536, 4096, 4096, 256);
    reduce_to_afrag<<<256, 256, 0, stream>>>(pbuf, slot, 16);
    pack_zs<<<512, 256, 0, stream>>>(o_qz, o_sc, zsb, 512, 4096, 4096, 131072);

    // attn = q @ Wo ; res2 = x + attn
    gemm_awq<<<dim3(64, 16), 256, 0, stream>>>(slot, zsb, o_qw, pbuf,
                                               512, 4096, 4096, 256);
    reduce_add_f32<<<256, 256, 0, stream>>>(pbuf, x, res2, 16);

    // h2 = rmsnorm(res2, ln2) -> Afrag ; zs for gu
    rmsnorm_k<<<128, 256, 0, stream>>>(res2, ln2_w, slot);
    pack_zs<<<2752, 256, 0, stream>>>(gu_qz, gu_sc, zsb, 2752, 22016, 22016, 704512);

    // gate_up = h2 @ Wgu   (344 tiles x SK3, kchunk 1408)
    gemm_awq<<<dim3(344, 3), 256, 0, stream>>>(slot, zsb, gu_qw, pbuf,
                                               2752, 22016, 4096, 1408);
    silu_mul<<<688, 256, 0, stream>>>(pbuf, act);
    pack_zs<<<1376, 256, 0, stream>>>(dn_qz, dn_sc, zsb, 512, 4096, 4096, 352256);

    // down = act @ Wdn   (64 tiles x SK16, kchunk 704); out = res2 + down
    gemm_awq<<<dim3(64, 16), 256, 0, stream>>>(act, zsb, dn_qw, pbuf,
                                               512, 4096, 11008, 704);
    reduce_add_f32<<<256, 256, 0, stream>>>(pbuf, res2, out, 16);
}